// Round 4
// baseline (285.787 us; speedup 1.0000x reference)
//
#include <hip/hip_runtime.h>

// Problem constants (from setup_inputs)
#define NB 8
#define NC 3
#define NT 32
#define NH 224
#define NW 224
#define DIFF 16
#define INV_SCALE (224.0f / 240.0f)   // in/out = 14/15

#define TILE_ROWS 16                  // output rows per block
#define TILES_PER_FRAME (NH / TILE_ROWS)   // 14
#define NFRAMES (NB * NC * NT)        // 768

// VMEM-issue-bound model (R3): 80 wave-VMEM instrs/thread-col ~= 78 us/CU.
// This version cuts full-cost loads 64 -> ~17 via two in-register reuse axes:
//  - vertical: y-taps are wave-uniform; row ry's bottom pair == row ry+1's
//    top pair (carry in registers, uniform select)
//  - horizontal: w[x0+1] lives in lane x+1 (or x+2 at the 1-in-15 repeat
//    column; never further since step=14/15 -> two repeats can't be adjacent).
//    One __shfl replaces the second gather; ~8 boundary lanes/block use an
//    exec-masked fallback load. Shfl moves exact bits -> numerics unchanged.
__global__ __launch_bounds__(256) void shake_crop_reuse_kernel(
    const float* __restrict__ video,
    const int* __restrict__ shake_h,
    const int* __restrict__ shake_w,
    float* __restrict__ out)
{
    const int tid  = threadIdx.x;
    const int f    = blockIdx.x / TILES_PER_FRAME;   // frame index (b*C+c)*T + t
    const int tile = blockIdx.x - f * TILES_PER_FRAME;
    if (tid >= NW) return;            // 224 compute lanes; no barriers anywhere

    const int t  = f % NT;
    const int sh = shake_h[t];        // wave-uniform
    const int sw = shake_w[t];
    const int ybase = tile * TILE_ROWS;

    // Per-column horizontal weights (once per thread)
    const int x = tid;
    float ix = fminf(fmaxf((x + sw + 0.5f) * INV_SCALE - 0.5f, 0.0f), (float)(NW - 1));
    int   x0 = (int)ix;
    float fx = ix - (float)x0;
    int   x1 = min(x0 + 1, NW - 1);

    // Which lane holds w[x0+1]? lane x+1 if its x0 advanced, else lane x+2.
    // (step = 14/15: if x0(x+1)==x0 then frac(ix)<1/15, so ix+2*step lands in
    //  [1.867,1.933) past floor(ix) -> x0(x+2)==x0+1 exactly.)
    float ixn = fminf(fmaxf((x + 1 + sw + 0.5f) * INV_SCALE - 0.5f, 0.0f), (float)(NW - 1));
    int   x0n = (int)ixn;
    const int  srcLane = (x0n == x0 + 1) ? (x + 1) : (x + 2);
    const bool canShfl = (srcLane < NW) && ((srcLane >> 6) == (x >> 6)); // active + same wave

    const float* frame = video + (size_t)f * (NH * NW);
    float* ocol = out + (size_t)f * (NH * NW) + (size_t)ybase * NW + x;
    const int ys = ybase + sh;

    // Prologue: top-row pair of the first output row
    float iyp = fminf(fmaxf((ys + 0.5f) * INV_SCALE - 0.5f, 0.0f), (float)(NH - 1));
    int   pY0 = (int)iyp;
    float pv00 = frame[pY0 * NW + x0];
    float pv01 = __shfl(pv00, srcLane);
    if (!canShfl) pv01 = frame[pY0 * NW + x1];
    int   pY1 = -1;                    // no bottom row carried yet
    float pv10 = 0.0f, pv11 = 0.0f;

    #pragma unroll
    for (int ry = 0; ry < TILE_ROWS; ++ry) {
        float iy = fminf(fmaxf((ys + ry + 0.5f) * INV_SCALE - 0.5f, 0.0f), (float)(NH - 1));
        int   y0 = (int)iy;            // wave-uniform
        float fy = iy - (float)y0;
        int   y1 = min(y0 + 1, NH - 1);

        // Top pair: advance (y0==pY1) -> carried bottom; repeat/first -> carried top.
        // y0 is monotone with step<=1, so these two cases are exhaustive.
        float v00, v01;
        if (y0 == pY1) { v00 = pv10; v01 = pv11; }
        else           { v00 = pv00; v01 = pv01; }

        // Bottom pair: one gather + one shfl (+ masked edge fallback)
        float v10 = frame[y1 * NW + x0];
        float v11 = __shfl(v10, srcLane);
        if (!canShfl) v11 = frame[y1 * NW + x1];

        float top = v00 + fx * (v01 - v00);
        float bot = v10 + fx * (v11 - v10);
        float v   = top + fy * (bot - top);
        ocol[(size_t)ry * NW] = fminf(fmaxf(v, 0.0f), 1.0f);   // coalesced 256B/wave

        pY0 = y0; pY1 = y1;
        pv00 = v00; pv01 = v01; pv10 = v10; pv11 = v11;
    }
}

extern "C" void kernel_launch(void* const* d_in, const int* in_sizes, int n_in,
                              void* d_out, int out_size, void* d_ws, size_t ws_size,
                              hipStream_t stream) {
    const float* video   = (const float*)d_in[0];
    const int*   shake_h = (const int*)d_in[1];
    const int*   shake_w = (const int*)d_in[2];
    float*       out     = (float*)d_out;

    const int grid = NFRAMES * TILES_PER_FRAME;   // 10752 blocks, 8/CU
    shake_crop_reuse_kernel<<<grid, 256, 0, stream>>>(video, shake_h, shake_w, out);
}

// Round 5
// 262.587 us; speedup vs baseline: 1.0883x; 1.0883x over previous
//
#include <hip/hip_runtime.h>

// Problem constants (from setup_inputs)
#define NB 8
#define NC 3
#define NT 32
#define NH 224
#define NW 224
#define DIFF 16
#define INV_SCALE (224.0f / 240.0f)   // in/out = 14/15

#define TILE_ROWS 16                  // output rows per block
#define TILES_PER_FRAME (NH / TILE_ROWS)   // 14
#define NFRAMES (NB * NC * NT)        // 768

// R5: R3's structure (no barriers / no LDS / no DS ops / independent gathers)
// + vertical register carry only (the part of R4 that was pure win).
// R4 post-mortem: __shfl (ds_bpermute) serialized each row into a
// load->lgkm->shuffle chain (VGPR fell to 16, LDS-conflict counter lit up,
// 105us). Here every load is an independent global gather the compiler can
// software-pipeline; loads/thread drop 64 -> 34 vs R3.
// Issue model (calibrated on R3: ~15cy/gather, ~5cy/store):
// 42 blk/CU x 4 waves x (34*15 + 16*5) cy ~= 41 us.
__global__ __launch_bounds__(256) void shake_crop_vcarry_kernel(
    const float* __restrict__ video,
    const int* __restrict__ shake_h,
    const int* __restrict__ shake_w,
    float* __restrict__ out)
{
    const int tid  = threadIdx.x;
    const int f    = blockIdx.x / TILES_PER_FRAME;   // frame index (b*C+c)*T + t
    const int tile = blockIdx.x - f * TILES_PER_FRAME;
    if (tid >= NW) return;            // 224 compute lanes; no barriers anywhere

    const int t  = f % NT;
    const int sh = shake_h[t];        // wave-uniform -> scalar
    const int sw = shake_w[t];
    const int ybase = tile * TILE_ROWS;

    // Per-column horizontal weights (once per thread)
    const int x = tid;
    float ix = fminf(fmaxf((x + sw + 0.5f) * INV_SCALE - 0.5f, 0.0f), (float)(NW - 1));
    int   x0 = (int)ix;
    float fx = ix - (float)x0;
    int   x1 = min(x0 + 1, NW - 1);

    const float* frame = video + (size_t)f * (NH * NW);
    float* ocol = out + (size_t)f * (NH * NW) + (size_t)ybase * NW + x;
    const int ys = ybase + sh;

    // Prologue: top-row pair of the first output row (2 independent gathers)
    float iyp = fminf(fmaxf((ys + 0.5f) * INV_SCALE - 0.5f, 0.0f), (float)(NH - 1));
    int   pY0 = (int)iyp;
    float pv00 = frame[pY0 * NW + x0];
    float pv01 = frame[pY0 * NW + x1];
    int   pY1 = -1;                    // no bottom row carried yet
    float pv10 = 0.0f, pv11 = 0.0f;

    #pragma unroll
    for (int ry = 0; ry < TILE_ROWS; ++ry) {
        float iy = fminf(fmaxf((ys + ry + 0.5f) * INV_SCALE - 0.5f, 0.0f), (float)(NH - 1));
        int   y0 = (int)iy;            // wave-uniform; monotone, step <= 1
        float fy = iy - (float)y0;
        int   y1 = min(y0 + 1, NH - 1);

        // Top pair: advance (y0==pY1) -> take carried bottom pair;
        // repeat/first -> keep carried top pair. Exhaustive since step<=1.
        // (Carry logic numerics verified by R4's passing run.)
        float v00, v01;
        if (y0 == pY1) { v00 = pv10; v01 = pv11; }
        else           { v00 = pv00; v01 = pv01; }

        // Bottom pair: 2 independent gathers (same cacheline almost always)
        float v10 = frame[y1 * NW + x0];
        float v11 = frame[y1 * NW + x1];

        float top = v00 + fx * (v01 - v00);
        float bot = v10 + fx * (v11 - v10);
        float v   = top + fy * (bot - top);
        ocol[(size_t)ry * NW] = fminf(fmaxf(v, 0.0f), 1.0f);   // coalesced 256B/wave

        pY0 = y0; pY1 = y1;
        pv00 = v00; pv01 = v01; pv10 = v10; pv11 = v11;
    }
}

extern "C" void kernel_launch(void* const* d_in, const int* in_sizes, int n_in,
                              void* d_out, int out_size, void* d_ws, size_t ws_size,
                              hipStream_t stream) {
    const float* video   = (const float*)d_in[0];
    const int*   shake_h = (const int*)d_in[1];
    const int*   shake_w = (const int*)d_in[2];
    float*       out     = (float*)d_out;

    const int grid = NFRAMES * TILES_PER_FRAME;   // 10752 blocks, 8/CU
    shake_crop_vcarry_kernel<<<grid, 256, 0, stream>>>(video, shake_h, shake_w, out);
}